// Round 1
// 103.481 us; speedup vs baseline: 1.0137x; 1.0137x over previous
//
#include <hip/hip_runtime.h>

// 16-qubit, 2-layer circuit, batch 32.  Circuit = P*R1*P*R0 (P = CNOT-ring permutation).
// f(i) = i ^ (i>>1) ^ (bit0(i)?0xC000:0);  f^{-1} = suffix-xor cascade.
// Cooperative fused kernel (3 phases, per-batch atomic producer/consumer sync) with
// occupancy pre-check + return-code-checked fallback to the verified R3 3-kernel path.
//
// R4 change: sync-primitive hygiene. The old wait16 polled with an ACQUIRE agent
// atomic load — on gfx950 every such load emits buffer_inv (full per-XCD L2
// invalidate). 512 pollers -> an L2 invalidate every ~10 cycles per XCD for the
// whole wait window, destroying all concurrent streaming traffic. Now: RELAXED
// poll + ONE trailing acquire fence per wave. signal() likewise drops its
// redundant full __threadfence() (the RELEASE fetch_add already publishes).

#define NT 256

__device__ __forceinline__ int fperm(int x) {
  int y = x ^ (x >> 1);
  y ^= (x & 1) ? 0xC000 : 0;
  return y & 0xFFFF;
}

__device__ __forceinline__ int finv16(int x) {
  int s = x;
  s ^= s >> 1; s ^= s >> 2; s ^= s >> 4; s ^= s >> 8;
  int b15 = ((s ^ (s >> 15)) & 1) << 15;
  return (s & 0x7FFF) | b15;
}

__device__ __forceinline__ int swz1(int l) { return l ^ ((l >> 4) & 31); }
__device__ __forceinline__ int swz2(int l) { return l ^ ((l >> 5) & 31); }

__device__ __forceinline__ void compute_gates(const float* __restrict__ th, float* gsh) {
  int tid = threadIdx.x;
  if (tid < 32) {
    int l = tid >> 4, q = tid & 15;
    float tx = th[l * 48 + q], ty = th[l * 48 + 16 + q], tz = th[l * 48 + 32 + q];
    float cx, sx, cy, sy, cz, sz;
    sincosf(0.5f * tx, &sx, &cx);
    sincosf(0.5f * ty, &sy, &cy);
    sincosf(0.5f * tz, &sz, &cz);
    float m00r = cy * cx, m00i =  sy * sx;
    float m01r = -sy * cx, m01i = -cy * sx;
    float m10r =  sy * cx, m10i = -cy * sx;
    float m11r =  cy * cx, m11i = -sy * sx;
    float* G = gsh + tid * 8;
    G[0] = cz * m00r + sz * m00i;  G[1] = cz * m00i - sz * m00r;
    G[2] = cz * m01r + sz * m01i;  G[3] = cz * m01i - sz * m01r;
    G[4] = cz * m10r - sz * m10i;  G[5] = cz * m10i + sz * m10r;
    G[6] = cz * m11r - sz * m11i;  G[7] = cz * m11i + sz * m11r;
  }
}

template <int MK, int SK, int N>
__device__ __forceinline__ void greg(float (&ar)[N], float (&ai)[N],
                                     const float* G, int c) {
  const float4* G4 = (const float4*)G;
  float4 r0 = G4[0], r1 = G4[1];
  bool sw = (c != 0);
  float h00r = sw ? r1.z : r0.x, h00i = sw ? r1.w : r0.y;
  float h01r = sw ? r1.x : r0.z, h01i = sw ? r1.y : r0.w;
  float h10r = sw ? r0.z : r1.x, h10i = sw ? r0.w : r1.y;
  float h11r = sw ? r0.x : r1.z, h11i = sw ? r0.y : r1.w;
  constexpr int PV = MK & (-MK);
#pragma unroll
  for (int k = 0; k < N; k++) {
    if (k & PV) continue;
    const int k2 = k ^ MK;
    const int p0 = __builtin_popcount(k & SK) & 1;
    const int ka = p0 ? k2 : k;
    const int kb = p0 ? k : k2;
    float xr = ar[ka], xi = ai[ka], yr = ar[kb], yi = ai[kb];
    ar[ka] = h00r * xr - h00i * xi + h01r * yr - h01i * yi;
    ai[ka] = h00r * xi + h00i * xr + h01r * yi + h01i * yr;
    ar[kb] = h10r * xr - h10i * xi + h11r * yr - h11i * yi;
    ai[kb] = h10r * xi + h10i * xr + h11r * yi + h11i * yr;
  }
}

// ====================== Phase bodies as device functions ======================

__device__ __forceinline__ void phaseA_body(int t, int bbase, int wb,
                                            const float* gsh,
                                            float* sre, float* sim,
                                            const float* __restrict__ xre,
                                            const float* __restrict__ xim,
                                            float2* __restrict__ ws) {
  float ar[16], ai[16];
  int base = bbase + (wb << 12);
  const float4* xr4 = (const float4*)(xre + base + (t << 4));
  const float4* xi4 = (const float4*)(xim + base + (t << 4));
#pragma unroll
  for (int q = 0; q < 4; q++) {
    float4 v = xr4[q]; ar[4*q] = v.x; ar[4*q+1] = v.y; ar[4*q+2] = v.z; ar[4*q+3] = v.w;
    float4 w = xi4[q]; ai[4*q] = w.x; ai[4*q+1] = w.y; ai[4*q+2] = w.z; ai[4*q+3] = w.w;
  }
  __syncthreads();   // gsh ready (and sre/sim free)
  greg<1, 1>(ar, ai, gsh + 15 * 8, 0);
  greg<2, 2>(ar, ai, gsh + 14 * 8, 0);
  greg<4, 4>(ar, ai, gsh + 13 * 8, 0);
  greg<8, 8>(ar, ai, gsh + 12 * 8, 0);
#pragma unroll
  for (int k = 0; k < 16; k++) { int s = swz1((t << 4) | k); sre[s] = ar[k]; sim[s] = ai[k]; }
  __syncthreads();
#pragma unroll
  for (int k = 0; k < 16; k++) {
    int s = swz1((t & 15) | (k << 4) | ((t >> 4) << 8));
    ar[k] = sre[s]; ai[k] = sim[s];
  }
  greg<1, 1>(ar, ai, gsh + 11 * 8, 0);
  greg<2, 2>(ar, ai, gsh + 10 * 8, 0);
  greg<4, 4>(ar, ai, gsh + 9 * 8, 0);
  greg<8, 8>(ar, ai, gsh + 8 * 8, 0);
#pragma unroll
  for (int k = 0; k < 16; k++) {
    int s = swz1((t & 15) | (k << 4) | ((t >> 4) << 8));
    sre[s] = ar[k]; sim[s] = ai[k];
  }
  __syncthreads();
#pragma unroll
  for (int k = 0; k < 16; k++) {
    int s = swz1(t | (k << 8)); ar[k] = sre[s]; ai[k] = sim[s];
  }
  greg<1, 1>(ar, ai, gsh + 7 * 8, 0);
  greg<2, 2>(ar, ai, gsh + 6 * 8, 0);
  greg<4, 4>(ar, ai, gsh + 5 * 8, 0);
  greg<8, 8>(ar, ai, gsh + 4 * 8, 0);
#pragma unroll
  for (int k = 0; k < 16; k++)
    ws[base + t + (k << 8)] = make_float2(ar[k], ai[k]);
}

__device__ __forceinline__ void phaseB_body(int t, int bbase, int wb,
                                            const float* gsh,
                                            float* sre, float* sim,
                                            float2* __restrict__ ws) {
  float ar[16], ai[16];
#pragma unroll
  for (int k = 0; k < 16; k++) {
    float2 v = ws[bbase + t + (wb << 8) + (k << 12)];
    ar[k] = v.x; ai[k] = v.y;
  }
  int cA = (__popc(t) + __popc(wb)) & 1;   // parity of full bits 0..11
  greg<1, 1>(ar, ai, gsh + 3 * 8, 0);
  greg<2, 2>(ar, ai, gsh + 2 * 8, 0);
  greg<4, 4>(ar, ai, gsh + 1 * 8, 0);
  greg<8, 8>(ar, ai, gsh + 0 * 8, 0);
  greg<12, 7>(ar, ai, gsh + (16 + 0) * 8, cA);
  greg<6, 12>(ar, ai, gsh + (16 + 1) * 8, 0);
  greg<3, 14>(ar, ai, gsh + (16 + 2) * 8, 0);
  __syncthreads();   // sre/sim free
#pragma unroll
  for (int k = 0; k < 16; k++) {
    int s = swz2(t | (k << 8)); sre[s] = ar[k]; sim[s] = ai[k];
  }
  __syncthreads();
#pragma unroll
  for (int k = 0; k < 16; k++) {
    int s = swz2((k & 3) | (t << 2) | ((k >> 2) << 10));
    ar[k] = sre[s]; ai[k] = sim[s];
  }
  greg<13, 15>(ar, ai, gsh + (16 + 15) * 8, cA);
  greg<3, 14>(ar, ai, gsh + (16 + 14) * 8, cA);
#pragma unroll
  for (int k = 0; k < 16; k++) {
    int s = swz2((k & 3) | (t << 2) | ((k >> 2) << 10));
    sre[s] = ar[k]; sim[s] = ai[k];
  }
  __syncthreads();
#pragma unroll
  for (int k = 0; k < 16; k++) {
    int s = swz2((t & 1) | (k << 1) | ((t >> 1) << 5));
    ar[k] = sre[s]; ai[k] = sim[s];
  }
  {
    int cC = (__popc(t >> 1) + __popc(wb)) & 1;
    greg<3, 14>(ar, ai, gsh + (16 + 13) * 8, cC);
    greg<6, 12>(ar, ai, gsh + (16 + 12) * 8, cC);
    greg<12, 8>(ar, ai, gsh + (16 + 11) * 8, cC);
  }
#pragma unroll
  for (int k = 0; k < 16; k++) {
    int s = swz2((t & 1) | (k << 1) | ((t >> 1) << 5));
    sre[s] = ar[k]; sim[s] = ai[k];
  }
  __syncthreads();
#pragma unroll
  for (int k = 0; k < 16; k++) {
    int s = swz2((t & 15) | (k << 4) | ((t >> 4) << 8));
    ar[k] = sre[s]; ai[k] = sim[s];
  }
  {
    int cD = (__popc(t >> 4) + __popc(wb)) & 1;
    greg<3, 14>(ar, ai, gsh + (16 + 10) * 8, cD);
    greg<6, 12>(ar, ai, gsh + (16 + 9) * 8, cD);
    greg<12, 8>(ar, ai, gsh + (16 + 8) * 8, cD);
  }
#pragma unroll
  for (int k = 0; k < 16; k++) {
    int full = (t & 15) | (k << 4) | (wb << 8) | ((t >> 4) << 12);
    ws[bbase + full] = make_float2(ar[k], ai[k]);
  }
}

__device__ __forceinline__ void phaseC_body(int t, int bbase3, int g3,
                                            const float* gsh,
                                            const float2* __restrict__ ws,
                                            float* __restrict__ out) {
  int jt = t | (g3 << 13);
  float br[32], bi[32];
#pragma unroll
  for (int k = 0; k < 32; k++) {
    int j = jt | (k << 8);
    float2 v = ws[bbase3 + fperm(j)];
    br[k] = v.x; bi[k] = v.y;
  }
  greg<1, 1>(br, bi, gsh + (16 + 7) * 8, 0);
  greg<2, 2>(br, bi, gsh + (16 + 6) * 8, 0);
  greg<4, 4>(br, bi, gsh + (16 + 5) * 8, 0);
  greg<8, 8>(br, bi, gsh + (16 + 4) * 8, 0);
  greg<16, 16>(br, bi, gsh + (16 + 3) * 8, 0);
#pragma unroll
  for (int k = 0; k < 32; k++) {
    int j = jt | (k << 8);
    out[bbase3 + finv16(j)] = br[k] * br[k] + bi[k] * bi[k];
  }
}

// ====================== Fallback: verified R3 three-kernel path ======================

__global__ void __launch_bounds__(NT) pass1_k(const float* __restrict__ th,
                                              const float* __restrict__ xre,
                                              const float* __restrict__ xim,
                                              float2* __restrict__ ws) {
  __shared__ float gsh[256];
  __shared__ float sre[4096], sim[4096];
  int t = threadIdx.x;
  int blk = blockIdx.x, batch = blk >> 4, wb = blk & 15;
  compute_gates(th, gsh);
  phaseA_body(t, batch * 65536, wb, gsh, sre, sim, xre, xim, ws);
}

__global__ void __launch_bounds__(NT) pass2_k(const float* __restrict__ th,
                                              float2* __restrict__ ws) {
  __shared__ float gsh[256];
  __shared__ float sre[4096], sim[4096];
  int t = threadIdx.x;
  int blk = blockIdx.x, batch = blk >> 4, wb = blk & 15;
  compute_gates(th, gsh);
  __syncthreads();   // gsh ready before phaseB reads it
  phaseB_body(t, batch * 65536, wb, gsh, sre, sim, ws);
}

__global__ void __launch_bounds__(NT) pass3_k(const float* __restrict__ th,
                                              const float2* __restrict__ ws,
                                              float* __restrict__ out) {
  __shared__ float gsh[256];
  int t = threadIdx.x;
  int blk = blockIdx.x, batch = blk >> 3, g3 = blk & 7;
  compute_gates(th, gsh);
  __syncthreads();
  phaseC_body(t, batch * 65536, g3, gsh, ws, out);
}

// ====================== Cooperative fused kernel ======================

// Release side: each wave drains its own global stores to L2 (waitcnt only —
// no cache-wide ops), barrier, then ONE agent-scope RELEASE fetch_add by
// thread 0 (this emits the single buffer_wbl2 that publishes the whole
// block's L2-resident stores across XCDs).
__device__ __forceinline__ void signal(unsigned* cnt) {
  __threadfence_block();   // s_waitcnt vmcnt/lgkmcnt drain; no buffer_wbl2/inv
  __syncthreads();
  if (threadIdx.x == 0)
    __hip_atomic_fetch_add(cnt, 1u, __ATOMIC_RELEASE, __HIP_MEMORY_SCOPE_AGENT);
}

// Acquire side: RELAXED polls (plain device-coherent loads — NO buffer_inv per
// iteration), then exactly one acquire fence per wave after the count is
// reached. Relaxed-poll + trailing acquire fence is the standard fence-based
// synchronization pattern; semantics identical to the old acquire-poll.
__device__ __forceinline__ void wait16(unsigned* cnt) {
  if (threadIdx.x == 0) {
    while (__hip_atomic_load(cnt, __ATOMIC_RELAXED, __HIP_MEMORY_SCOPE_AGENT) < 16u)
      __builtin_amdgcn_s_sleep(2);
  }
  __syncthreads();
  // One L1/L2 invalidate per wave (4 per block), AFTER publication observed.
  __builtin_amdgcn_fence(__ATOMIC_ACQUIRE, "agent");
}

__global__ void __launch_bounds__(NT, 2)
fused_k(const float* __restrict__ th,
        const float* __restrict__ xre, const float* __restrict__ xim,
        float2* __restrict__ ws, float* __restrict__ out,
        unsigned* __restrict__ cnt1, unsigned* __restrict__ cnt2) {
  __shared__ float gsh[256];
  __shared__ float sre[4096], sim[4096];
  int t = threadIdx.x;
  int blk = blockIdx.x;
  int batch = blk >> 4, wb = blk & 15;
  int bbase = batch * 65536;

  compute_gates(th, gsh);
  phaseA_body(t, bbase, wb, gsh, sre, sim, xre, xim, ws);
  signal(&cnt1[batch]);

  wait16(&cnt1[batch]);
  phaseB_body(t, bbase, wb, gsh, sre, sim, ws);
  signal(&cnt2[batch]);

  if (blk >= 256) return;
  int batch3 = blk >> 3, g3 = blk & 7;
  wait16(&cnt2[batch3]);
  phaseC_body(t, batch3 * 65536, g3, gsh, ws, out);
}

// ====================== Launcher ======================

extern "C" void kernel_launch(void* const* d_in, const int* in_sizes, int n_in,
                              void* d_out, int out_size, void* d_ws, size_t ws_size,
                              hipStream_t stream) {
  const float* th  = (const float*)d_in[0];   // (2,3,16)
  const float* xre = (const float*)d_in[1];   // (32,65536)
  const float* xim = (const float*)d_in[2];   // (32,65536)
  float* out = (float*)d_out;                 // (32,65536) fp32

  float2* amp = (float2*)d_ws;                              // 16 MB state
  unsigned* cnt1 = (unsigned*)((char*)d_ws + (16u << 20));  // 32+32 counters
  unsigned* cnt2 = cnt1 + 32;

  // Occupancy pre-check (pure query, capture-safe): need >= 2 blocks/CU so all
  // 512 blocks are co-resident (spin-sync deadlock-free).
  int maxBlk = 0;
  hipError_t qrc = hipOccupancyMaxActiveBlocksPerMultiprocessor(
      &maxBlk, (const void*)fused_k, NT, 0);
  bool try_coop = (qrc == hipSuccess && maxBlk >= 2);

  bool coop_ok = false;
  if (try_coop) {
    hipMemsetAsync((void*)cnt1, 0, 64 * sizeof(unsigned), stream);
    void* args[] = {(void*)&th, (void*)&xre, (void*)&xim,
                    (void*)&amp, (void*)&out, (void*)&cnt1, (void*)&cnt2};
    hipError_t rc = hipLaunchCooperativeKernel((const void*)fused_k, dim3(512),
                                               dim3(NT), args, 0, stream);
    coop_ok = (rc == hipSuccess);
  }

  if (!coop_ok) {
    // Verified R3 path.
    pass1_k<<<512, NT, 0, stream>>>(th, xre, xim, amp);
    pass2_k<<<512, NT, 0, stream>>>(th, amp);
    pass3_k<<<256, NT, 0, stream>>>(th, amp, out);
  }
}